// Round 6
// baseline (278.823 us; speedup 1.0000x reference)
//
#include <hip/hip_runtime.h>
#include <cstdint>
#include <cstddef>

// MoE Router: logits = x[16384,2048] @ W[2048,64] + b; softmax; top-2 (renorm);
// z_loss = mean(lse^2)*1e-3.
// Output float layout: [0,32768) top2 probs, [32768,65536) top2 indices (as
// float), [65536] z_loss.
//
// Decomposition: 512 blocks x 256 threads; block = 32 tokens x 64 experts.
// thread = (tr, g, tc): tr=tid>>5 owns tokens tr*4..tr*4+3; g=(tid>>4)&1 owns
// the k-half of each 64-wide D-chunk; tc=tid&15 owns experts tc*4..tc*4+3.
// Per-thread 4x4 fp32 accumulator; g-halves reduced via __shfl_xor(.,16)
// (lane bit 4 == g). LDS bytes/FMA = 2.0; FMA-issue-bound by design
// (16384 fma/thread -> 27.3 us floor at 2 waves/SIMD lifetime).
//
// Bank math (audited): x reads = 4 addrs/instr, paired 2-way per bank-quad
// (free, m136); W reads = 32 distinct 16B addrs = 512B/instr = 4-cycle LDS-BW
// floor (not a fixable conflict). Stage->compute->barrier is the 2-phase
// minimum schedule (T3): loads issued before compute, drained at barrier.
// W served from per-XCD L2 (512KB << 4MB, ~8.5 TB/s demand vs 34.5 ceiling);
// HBM sees only x (~134 MB).

#define NTOK   16384
#define DIM    2048
#define NEXP   64
#define TT     32            // tokens per block
#define DC     64            // D-chunk (k per staged tile)
#define NCH    (DIM / DC)    // 32 chunks
#define ZCOEF  0.001f

__device__ __forceinline__ void gload_lds16(const float* g, float* l) {
  // async global->LDS, 16B/lane; LDS dest must be wave-uniform (it is: bases
  // depend only on wv + compile-time ii); global src is per-lane.
  __builtin_amdgcn_global_load_lds(
      (const __attribute__((address_space(1))) void*)g,
      (__attribute__((address_space(3))) void*)l,
      16, 0, 0);
}

__global__ __launch_bounds__(256) void moe_router_kernel(
    const float* __restrict__ x, const float* __restrict__ Wg,
    const float* __restrict__ bias, float* __restrict__ out)
{
  __shared__ float xs0[TT * DC], xs1[TT * DC];     // 2 x 8 KB
  __shared__ float ws0[DC * NEXP], ws1[DC * NEXP]; // 2 x 16 KB (total 48 KB)

  const int tid  = threadIdx.x;
  const int lane = tid & 63;
  const int wv   = tid >> 6;        // wave 0..3
  const int tc   = tid & 15;        // expert group: experts tc*4..tc*4+3
  const int g    = (tid >> 4) & 1;  // k-half of each chunk (lane bit 4)
  const int tr   = tid >> 5;        // token group 0..7: tokens tr*4..tr*4+3
  const int t0   = blockIdx.x * TT;

  const int lrow = lane >> 4;       // 0..3: row within one staging instr
  const int lcol = lane & 15;       // 16B block within a 256B row

  float acc[4][4];
#pragma unroll
  for (int i = 0; i < 4; ++i)
#pragma unroll
    for (int j = 0; j < 4; ++j) acc[i][j] = 0.f;

  // bias for this thread's 4 experts — load early, overlaps the K-loop
  float bb[4];
  *(float4*)bb = *(const float4*)&bias[tc << 2];

  auto stage = [&](float* xbuf, float* wbuf, int c) {
    const int d0 = c * DC;
    // x: wave wv stages token rows [wv*8, wv*8+8) — exactly the rows this
    // wave's tr groups read. LDS layout stays LINEAR (global_load_lds rule
    // #21); the SOURCE column-block is XOR-swizzled by (row>>2)&3 so the read
    // side (2 tr-rows x 2 g-blocks per ds_read_b128) is 2-way max (free).
#pragma unroll
    for (int ii = 0; ii < 2; ++ii) {
      const int r0   = wv * 8 + ii * 4;
      const int trow = r0 + lrow;
      const int sblk = lcol ^ ((trow >> 2) & 3);
      const float* gp = x + (size_t)(t0 + trow) * DIM + d0 + (sblk << 2);
      gload_lds16(gp, &xbuf[r0 * DC]);
    }
    // W: wave wv stages rows [wv*16, wv*16+16), linear. W reads move 512B
    // unique per instr — LDS-BW-saturated regardless of layout, no swizzle.
#pragma unroll
    for (int ii = 0; ii < 4; ++ii) {
      const int r0   = wv * 16 + ii * 4;
      const float* gp = Wg + (size_t)(d0 + r0 + lrow) * NEXP + (lcol << 2);
      gload_lds16(gp, &wbuf[r0 * NEXP]);
    }
  };

  const int dbase = g << 5;  // this thread's k-half within the chunk
  auto compute = [&](const float* __restrict__ xb, const float* __restrict__ wb) {
#pragma unroll
    for (int dq = 0; dq < 8; ++dq) {         // 8 k-quads of this g-half
      const int dd = dbase + (dq << 2);
      float xr[4][4], wr[4][4];
#pragma unroll
      for (int i = 0; i < 4; ++i) {
        const int t   = (tr << 2) + i;
        const int blk = (dd >> 2) ^ (tr & 3);   // matches staging swizzle
        *(float4*)xr[i] = *(const float4*)&xb[t * DC + (blk << 2)];
      }
#pragma unroll
      for (int k = 0; k < 4; ++k)
        *(float4*)wr[k] = *(const float4*)&wb[(dd + k) * NEXP + (tc << 2)];
#pragma unroll
      for (int k = 0; k < 4; ++k)
#pragma unroll
        for (int i = 0; i < 4; ++i)
#pragma unroll
          for (int j = 0; j < 4; ++j)
            acc[i][j] = fmaf(xr[i][k], wr[k][j], acc[i][j]);
    }
  };

  // prologue
  stage(xs0, ws0, 0);
  __syncthreads();

  // K-loop, manually 2x-unrolled so both LDS buffers are compile-time bases
  // (no runtime cur index -> ds_read offsets fold to immediates; rule #20).
  for (int c = 0; c < NCH; c += 2) {
    if (c + 1 < NCH) stage(xs1, ws1, c + 1);   // async; drained at barrier
    compute(xs0, ws0);
    __syncthreads();
    if (c + 2 < NCH) stage(xs0, ws0, c + 2);
    compute(xs1, ws1);
    __syncthreads();
  }

  // ---- epilogue (runs once; use precise expf/logf — cost is noise, and
  // z-loss is a 16384-term mean where 2-ulp fast-math error is avoidable
  // validation risk) ----
  // combine the two k-halves: lane bit 4 is g
#pragma unroll
  for (int i = 0; i < 4; ++i)
#pragma unroll
    for (int j = 0; j < 4; ++j) acc[i][j] += __shfl_xor(acc[i][j], 16);

#pragma unroll
  for (int i = 0; i < 4; ++i)
#pragma unroll
    for (int j = 0; j < 4; ++j) acc[i][j] += bb[j];

  const bool writer = (tc == 0) && (g == 0);
  float zacc = 0.f;
#pragma unroll
  for (int i = 0; i < 4; ++i) {
    // top-1 (tie-break: lowest index, matching jax.lax.top_k stability)
    float v0 = acc[i][0]; int i0 = tc * 4;
#pragma unroll
    for (int j = 1; j < 4; ++j) {
      if (acc[i][j] > v0) { v0 = acc[i][j]; i0 = tc * 4 + j; }
    }
#pragma unroll
    for (int off = 1; off <= 8; off <<= 1) {
      float ov = __shfl_xor(v0, off);
      int   oi = __shfl_xor(i0, off);
      if (ov > v0 || (ov == v0 && oi < i0)) { v0 = ov; i0 = oi; }
    }
    // top-2: best excluding i0
    float v1 = -3.402823466e38f; int i1 = 1 << 30;
#pragma unroll
    for (int j = 0; j < 4; ++j) {
      const int   e = tc * 4 + j;
      const float v = acc[i][j];
      if (e != i0 && (v > v1 || (v == v1 && e < i1))) { v1 = v; i1 = e; }
    }
#pragma unroll
    for (int off = 1; off <= 8; off <<= 1) {
      float ov = __shfl_xor(v1, off);
      int   oi = __shfl_xor(i1, off);
      if (ov > v1 || (ov == v1 && oi < i1)) { v1 = ov; i1 = oi; }
    }
    // softmax denominator over all 64 experts (for lse)
    float s = 0.f;
#pragma unroll
    for (int j = 0; j < 4; ++j) s += expf(acc[i][j] - v0);
#pragma unroll
    for (int off = 1; off <= 8; off <<= 1) s += __shfl_xor(s, off);

    const float lse = v0 + logf(s);
    zacc += lse * lse;

    const float e2 = expf(v1 - v0);
    const float p1 = 1.f / (1.f + e2);
    const float p2 = e2 * p1;

    if (writer) {
      const int t = t0 + (tr << 2) + i;
      float2 pp; pp.x = p1; pp.y = p2;
      *(float2*)&out[2 * t] = pp;
      float2 ii2; ii2.x = (float)i0; ii2.y = (float)i1;
      *(float2*)&out[2 * NTOK + 2 * t] = ii2;
    }
  }

  // zacc is replicated across the 32 (tc,g) lanes of each tr; wave holds two
  // tr groups (lane bit 5). One atomic per wave covering its 8 tokens.
  zacc += __shfl_xor(zacc, 32);
  if (lane == 0) atomicAdd(&out[4 * NTOK], zacc * (ZCOEF / (float)NTOK));
}

extern "C" void kernel_launch(void* const* d_in, const int* in_sizes, int n_in,
                              void* d_out, int out_size, void* d_ws, size_t ws_size,
                              hipStream_t stream) {
  const float* x  = (const float*)d_in[0];
  const float* Wg = (const float*)d_in[1];
  const float* b  = (const float*)d_in[2];
  float* out = (float*)d_out;

  // d_out is poisoned 0xAA before every timed launch — zero the z-loss cell.
  hipMemsetAsync(out + 4 * NTOK, 0, sizeof(float), stream);

  dim3 grid(NTOK / TT);   // 512 blocks -> 2 blocks/CU lifetime
  dim3 block(256);
  hipLaunchKernelGGL(moe_router_kernel, grid, block, 0, stream, x, Wg, b, out);
}